// Round 2
// baseline (33903.061 us; speedup 1.0000x reference)
//
#include <hip/hip_runtime.h>
#include <hip/hip_bf16.h>
#include <stdint.h>

typedef __bf16 bf16;
typedef __bf16 bf16x8 __attribute__((ext_vector_type(8)));
typedef float floatx4 __attribute__((ext_vector_type(4)));

#define T_STEPS 512
#define BATCH   64
#define HID     1024
#define GN      3072      // 3 gates * HID
#define KDIM    1024
#define TB      (T_STEPS*BATCH)   // 32768
#define PHALF   (64*3*3*1024)     // one t-parity half of the partial buffer (fp32 elems)

__device__ __forceinline__ float sigmoidf_(float x) {
  return 1.0f / (1.0f + __expf(-x));
}

__device__ __forceinline__ void wait_ge(unsigned int* p, unsigned int target) {
  if (__hip_atomic_load(p, __ATOMIC_RELAXED, __HIP_MEMORY_SCOPE_AGENT) < target) {
    do { __builtin_amdgcn_s_sleep(1); }
    while (__hip_atomic_load(p, __ATOMIC_RELAXED, __HIP_MEMORY_SCOPE_AGENT) < target);
  }
  __builtin_amdgcn_fence(__ATOMIC_ACQUIRE, "agent");  // make producers' stores visible
}

// ---------------- small prep kernels ----------------

__global__ void cvt_f32_to_bf16(const float* __restrict__ src, bf16* __restrict__ dst, int n4) {
  int i = blockIdx.x * blockDim.x + threadIdx.x;
  if (i < n4) {
    float4 v = ((const float4*)src)[i];
    union { bf16 h[4]; uint2 u; } p;
    p.h[0] = (bf16)v.x; p.h[1] = (bf16)v.y; p.h[2] = (bf16)v.z; p.h[3] = (bf16)v.w;
    ((uint2*)dst)[i] = p.u;
  }
}

__global__ void combine_bias(const float* __restrict__ a, const float* __restrict__ b,
                             float* __restrict__ o, int n) {
  int i = blockIdx.x * blockDim.x + threadIdx.x;
  if (i < n) o[i] = a[i] + b[i];
}

__global__ void sigmoid_vec(const float* __restrict__ f, float* __restrict__ o, int n) {
  int i = blockIdx.x * blockDim.x + threadIdx.x;
  if (i < n) o[i] = sigmoidf_(f[i]);
}

__global__ void zero_words(uint32_t* __restrict__ p, int n) {
  int i = blockIdx.x * blockDim.x + threadIdx.x;
  if (i < n) p[i] = 0u;
}

// ---------------- big GEMM: C[M][3072] = A[M][1024] @ W[3072][1024]^T + bias ----------------

__global__ __launch_bounds__(256) void gemm_nt_bias(
    const bf16* __restrict__ A,     // [M][1024] row-major
    const bf16* __restrict__ W,     // [3072][1024] row-major
    const float* __restrict__ bias, // [3072]
    bf16* __restrict__ C)           // [M][3072]
{
  __shared__ __align__(16) bf16 As[128][72];
  __shared__ __align__(16) bf16 Bs[128][72];
  const int tid  = threadIdx.x;
  const int lane = tid & 63;
  const int wave = tid >> 6;
  const int wm = (wave >> 1) * 64;
  const int wn = (wave & 1) * 64;
  const size_t m0 = (size_t)blockIdx.x * 128;
  const size_t n0 = (size_t)blockIdx.y * 128;
  const int fr = lane & 15, fk = (lane >> 4) * 8;

  floatx4 acc[4][4] = {};

  for (int k0 = 0; k0 < KDIM; k0 += 64) {
#pragma unroll
    for (int i = 0; i < 4; ++i) {
      int idx = tid + i * 256;
      int row = idx >> 3, seg = idx & 7;
      *(uint4*)&As[row][seg * 8] = *(const uint4*)(A + (m0 + row) * KDIM + k0 + seg * 8);
      *(uint4*)&Bs[row][seg * 8] = *(const uint4*)(W + (n0 + row) * KDIM + k0 + seg * 8);
    }
    __syncthreads();
#pragma unroll
    for (int ks = 0; ks < 2; ++ks) {
      bf16x8 af[4], bv[4];
#pragma unroll
      for (int i = 0; i < 4; ++i) af[i] = *(const bf16x8*)&As[wm + i * 16 + fr][ks * 32 + fk];
#pragma unroll
      for (int j = 0; j < 4; ++j) bv[j] = *(const bf16x8*)&Bs[wn + j * 16 + fr][ks * 32 + fk];
#pragma unroll
      for (int i = 0; i < 4; ++i)
#pragma unroll
        for (int j = 0; j < 4; ++j)
          acc[i][j] = __builtin_amdgcn_mfma_f32_16x16x32_bf16(af[i], bv[j], acc[i][j], 0, 0, 0);
    }
    __syncthreads();
  }

  const int col0 = lane & 15, row0 = (lane >> 4) * 4;
#pragma unroll
  for (int j = 0; j < 4; ++j) {
    const size_t n = n0 + wn + j * 16 + col0;
    const float bval = bias[n];
#pragma unroll
    for (int i = 0; i < 4; ++i) {
#pragma unroll
      for (int r = 0; r < 4; ++r) {
        const size_t m = m0 + wm + i * 16 + row0 + r;
        C[m * GN + n] = (bf16)(acc[i][j][r] + bval);
      }
    }
  }
}

// ---------------- persistent cooperative recurrent layer ----------------
// 256 blocks = jt (0..63, j-tile of 16 cols for all 3 gates) x ks (0..3, K-split of 256).
// B (R-slice) lives in registers for the whole 512-step loop. ks!=0 blocks ship fp32
// partials to the ks==0 "reducer" block, which keeps c in registers and fuses the
// gate/cell epilogue. Handshake: monotone device-scope atomic counters + agent fences.
// Partials are double-buffered on t&1 (overwrite-safety proven via the hcnt chain).

__global__ __launch_bounds__(256, 1) void rec_layer(
    const bf16* __restrict__ zb,      // [64][1024] zeros (t=0 input)
    bf16* __restrict__ hseq,          // layer0: [512][64][1024]; layer1 (rolling): [2][64][1024]
    int rolling,
    const bf16* __restrict__ R,       // [3072][1024]
    const bf16* __restrict__ Gx,      // [512][64][3072]  x-proj + biases
    const float* __restrict__ fg,     // [1024] sigmoid(f)
    float* __restrict__ out_f,        // layer1: [512][64][1024] fp32 main output; else nullptr
    float* __restrict__ hfin,         // [64][1024] fp32 h_final slot
    float* __restrict__ cfin,         // [64][1024] fp32 c_final slot
    float* __restrict__ Pbuf,         // [2][64][3][3][64][16] fp32 partials
    unsigned int* pcnt,               // [64]  partial arrivals per jt (monotone)
    unsigned int* hcnt)               // [4]   h-slice arrivals per ks-group (monotone)
{
  const int tid  = threadIdx.x;
  const int lane = tid & 63;
  const int w    = tid >> 6;          // wave: batch rows [w*16, w*16+16)
  const int jt   = blockIdx.x & 63;
  const int ks   = blockIdx.x >> 6;   // K-slice [ks*256, ks*256+256)
  const int cq   = lane >> 4;         // 0..3
  const int cr   = lane & 15;         // 0..15

  // ---- one-time: B fragments into registers (96 VGPRs) ----
  bf16x8 Bf[3][8];
#pragma unroll
  for (int g = 0; g < 3; ++g)
#pragma unroll
    for (int kk = 0; kk < 8; ++kk)
      Bf[g][kk] = *(const bf16x8*)(R + (size_t)(g * HID + jt * 16 + cr) * KDIM
                                     + ks * 256 + kk * 32 + cq * 8);

  const float fgj = fg[jt * 16 + cr];
  floatx4 c = {0.f, 0.f, 0.f, 0.f};   // persistent cell state (reducer only uses it)

  for (int t = 0; t < T_STEPS; ++t) {
    // h_{t-1} cols [ks*256,..) are produced by reducers jt' in [16*ks, 16*ks+16)
    if (t > 0) wait_ge(&hcnt[ks], 16u * (unsigned)t);
    const bf16* hp;
    if (t == 0) hp = zb;
    else {
      int rs = rolling ? ((t - 1) & 1) : (t - 1);
      hp = hseq + (size_t)rs * (BATCH * HID);
    }

    // ---- A fragments straight from global (L2/L3-hot) + MFMA ----
    const bf16* Ab = hp + (size_t)(w * 16 + cr) * HID + ks * 256 + cq * 8;
    bf16x8 af[8];
#pragma unroll
    for (int kk = 0; kk < 8; ++kk) af[kk] = *(const bf16x8*)(Ab + kk * 32);
    floatx4 a0 = {0.f, 0.f, 0.f, 0.f}, a1 = a0, a2 = a0;
#pragma unroll
    for (int kk = 0; kk < 8; ++kk) {
      a0 = __builtin_amdgcn_mfma_f32_16x16x32_bf16(af[kk], Bf[0][kk], a0, 0, 0, 0);
      a1 = __builtin_amdgcn_mfma_f32_16x16x32_bf16(af[kk], Bf[1][kk], a1, 0, 0, 0);
      a2 = __builtin_amdgcn_mfma_f32_16x16x32_bf16(af[kk], Bf[2][kk], a2, 0, 0, 0);
    }

    float* Pb = Pbuf + (size_t)(t & 1) * PHALF;
    const int rowoff = (w * 16 + cq * 4) * 16 + cr;

    if (ks != 0) {
      // ---- ship partial to reducer ----
      float* P = Pb + (size_t)(jt * 3 + (ks - 1)) * 3072 + rowoff;
#pragma unroll
      for (int r = 0; r < 4; ++r) {
        P[r * 16]        = a0[r];
        P[1024 + r * 16] = a1[r];
        P[2048 + r * 16] = a2[r];
      }
      __syncthreads();
      if (tid == 0) {
        __builtin_amdgcn_fence(__ATOMIC_RELEASE, "agent");
        __hip_atomic_fetch_add(&pcnt[jt], 1u, __ATOMIC_RELEASE, __HIP_MEMORY_SCOPE_AGENT);
      }
    } else {
      // ---- reducer: prefetch Gx before spinning ----
      const bf16* gx = Gx + (size_t)t * (BATCH * GN)
                          + (size_t)(w * 16 + cq * 4) * GN + jt * 16 + cr;
      float gxv[3][4];
#pragma unroll
      for (int g = 0; g < 3; ++g)
#pragma unroll
        for (int r = 0; r < 4; ++r)
          gxv[g][r] = (float)gx[(size_t)r * GN + g * HID];

      wait_ge(&pcnt[jt], 3u * (unsigned)(t + 1));

      const float* P = Pb + (size_t)(jt * 3) * 3072 + rowoff;
#pragma unroll
      for (int ksp = 0; ksp < 3; ++ksp) {
#pragma unroll
        for (int r = 0; r < 4; ++r) {
          a0[r] += P[ksp * 3072 + r * 16];
          a1[r] += P[ksp * 3072 + 1024 + r * 16];
          a2[r] += P[ksp * 3072 + 2048 + r * 16];
        }
      }

      size_t wslot = rolling ? (size_t)(t & 1) : (size_t)t;
      bf16* hw = hseq + wslot * (BATCH * HID)
                      + (size_t)(w * 16 + cq * 4) * HID + jt * 16 + cr;
      float* ow = out_f ? (out_f + (size_t)t * (BATCH * HID)
                                 + (size_t)(w * 16 + cq * 4) * HID + jt * 16 + cr)
                        : nullptr;
#pragma unroll
      for (int r = 0; r < 4; ++r) {
        float ig = sigmoidf_(a0[r] + gxv[0][r]);
        float og = sigmoidf_(a1[r] + gxv[1][r]);
        float zg = sigmoidf_(a2[r] + gxv[2][r]);
        c[r] = c[r] * fgj + zg - ig;
        float h = sigmoidf_(c[r]) - og;
        hw[(size_t)r * HID] = (bf16)h;
        if (ow) ow[(size_t)r * HID] = h;
        if (t == T_STEPS - 1) {
          int b = w * 16 + cq * 4 + r;
          hfin[(size_t)b * HID + jt * 16 + cr] = h;
          cfin[(size_t)b * HID + jt * 16 + cr] = c[r];
        }
      }
      __syncthreads();
      if (tid == 0) {
        __builtin_amdgcn_fence(__ATOMIC_RELEASE, "agent");
        __hip_atomic_fetch_add(&hcnt[jt >> 4], 1u, __ATOMIC_RELEASE, __HIP_MEMORY_SCOPE_AGENT);
      }
    }
  }
}

// ---------------- launch ----------------

extern "C" void kernel_launch(void* const* d_in, const int* in_sizes, int n_in,
                              void* d_out, int out_size, void* d_ws, size_t ws_size,
                              hipStream_t stream) {
  const float* x   = (const float*)d_in[0];
  const float* W0  = (const float*)d_in[1];
  const float* R0  = (const float*)d_in[2];
  const float* bi0 = (const float*)d_in[3];
  const float* bh0 = (const float*)d_in[4];
  const float* f0  = (const float*)d_in[5];
  const float* W1  = (const float*)d_in[6];
  const float* R1  = (const float*)d_in[7];
  const float* bi1 = (const float*)d_in[8];
  const float* bh1 = (const float*)d_in[9];
  const float* f1  = (const float*)d_in[10];
  float* out = (float*)d_out;

  char* ws = (char*)d_ws;
  size_t off = 0;
  auto alloc = [&](size_t bytes) {
    char* p = ws + off;
    off += (bytes + 255) & ~(size_t)255;
    return p;
  };
  bf16* W0b = (bf16*)alloc((size_t)GN * KDIM * 2);
  bf16* R0b = (bf16*)alloc((size_t)GN * KDIM * 2);
  bf16* W1b = (bf16*)alloc((size_t)GN * KDIM * 2);
  bf16* R1b = (bf16*)alloc((size_t)GN * KDIM * 2);
  bf16* xb  = (bf16*)alloc((size_t)TB * KDIM * 2);
  bf16* h0b = (bf16*)alloc((size_t)TB * HID * 2);       // layer0 h sequence (GEMM1 input)
  bf16* Gx  = (bf16*)alloc((size_t)TB * GN * 2);
  float* b0c = (float*)alloc(GN * 4);
  float* b1c = (float*)alloc(GN * 4);
  float* fg0 = (float*)alloc(HID * 4);
  float* fg1 = (float*)alloc(HID * 4);
  // flags + zb contiguous (zeroed in one kernel each launch)
  unsigned int* flags = (unsigned int*)alloc(256 * 4);  // pcnt0[64] hcnt0[4] pcnt1[64] hcnt1[4]
  bf16* zb = (bf16*)alloc((size_t)BATCH * HID * 2);
  bf16* h1roll = (bf16*)alloc((size_t)2 * BATCH * HID * 2);
  float* Pbuf = (float*)alloc((size_t)2 * PHALF * 4);

  unsigned int* pcnt0 = flags;
  unsigned int* hcnt0 = flags + 64;
  unsigned int* pcnt1 = flags + 68;
  unsigned int* hcnt1 = flags + 132;

  float* fin = out + (size_t)T_STEPS * BATCH * HID;
  float* hfin0 = fin;
  float* hfin1 = fin + (size_t)BATCH * HID;
  float* cfin0 = fin + (size_t)2 * BATCH * HID;
  float* cfin1 = fin + (size_t)3 * BATCH * HID;

  // --- prep ---
  {
    int n4 = GN * KDIM / 4;
    int blocks = (n4 + 255) / 256;
    cvt_f32_to_bf16<<<blocks, 256, 0, stream>>>(W0, W0b, n4);
    cvt_f32_to_bf16<<<blocks, 256, 0, stream>>>(R0, R0b, n4);
    cvt_f32_to_bf16<<<blocks, 256, 0, stream>>>(W1, W1b, n4);
    cvt_f32_to_bf16<<<blocks, 256, 0, stream>>>(R1, R1b, n4);
  }
  {
    int n4 = TB * KDIM / 4;
    cvt_f32_to_bf16<<<(n4 + 255) / 256, 256, 0, stream>>>(x, xb, n4);
  }
  combine_bias<<<(GN + 255) / 256, 256, 0, stream>>>(bi0, bh0, b0c, GN);
  combine_bias<<<(GN + 255) / 256, 256, 0, stream>>>(bi1, bh1, b1c, GN);
  sigmoid_vec<<<(HID + 255) / 256, 256, 0, stream>>>(f0, fg0, HID);
  sigmoid_vec<<<(HID + 255) / 256, 256, 0, stream>>>(f1, fg1, HID);
  {
    int nwords = (256 * 4 + BATCH * HID * 2) / 4;  // flags + zb
    zero_words<<<(nwords + 255) / 256, 256, 0, stream>>>((uint32_t*)flags, nwords);
  }

  // --- layer 0 ---
  gemm_nt_bias<<<dim3(TB / 128, GN / 128), 256, 0, stream>>>(xb, W0b, b0c, Gx);
  {
    int roll = 0;
    float* nullf = nullptr;
    void* args[] = {&zb, &h0b, &roll, &R0b, &Gx, &fg0, &nullf,
                    &hfin0, &cfin0, &Pbuf, &pcnt0, &hcnt0};
    hipLaunchCooperativeKernel((const void*)rec_layer, dim3(256), dim3(256), args, 0, stream);
  }

  // --- layer 1 ---
  gemm_nt_bias<<<dim3(TB / 128, GN / 128), 256, 0, stream>>>(h0b, W1b, b1c, Gx);
  {
    int roll = 1;
    void* args[] = {&zb, &h1roll, &roll, &R1b, &Gx, &fg1, &out,
                    &hfin1, &cfin1, &Pbuf, &pcnt1, &hcnt1};
    hipLaunchCooperativeKernel((const void*)rec_layer, dim3(256), dim3(256), args, 0, stream);
  }
}